// Round 9
// baseline (1006.527 us; speedup 1.0000x reference)
//
#include <hip/hip_runtime.h>

#define BT    8      // batch tile per block
#define HID   64
#define SEQ   512
#define NOUT  12
#define XST   513    // padded x row stride (conflict-free per-lane batch reads)
#define KPD   36     // frag row stride in dwords (16B-aligned)

typedef float  f32x4  __attribute__((ext_vector_type(4)));
typedef short  bf16x8 __attribute__((ext_vector_type(8)));
typedef unsigned int   u32;
typedef unsigned short u16;

union FW { bf16x8 v; u32 w[4]; uint4 q; };

__device__ __forceinline__ float sigf(float x)       { return 1.f / (1.f + __expf(-x)); }
__device__ __forceinline__ float tanhf_fast(float x) { return 1.f - 2.f / (1.f + __expf(2.f * x)); }
__device__ __forceinline__ u32 packbf2(float a, float b) {
    return (__float_as_uint(a) >> 16) | (__float_as_uint(b) & 0xFFFF0000u);
}
__device__ __forceinline__ float trunc_bf(float a) {
    return __uint_as_float(__float_as_uint(a) & 0xFFFF0000u);
}
__device__ __forceinline__ u16 bf_hi(float a) { return (u16)(__float_as_uint(a) >> 16); }
__device__ __forceinline__ u16 bf_lo(float a) {
    float r = a - trunc_bf(a);
    return (u16)(__float_as_uint(r) >> 16);
}
// Split 8 consecutive f32 into hi/lo bf16x8 fragments (element j <-> k-offset j).
__device__ __forceinline__ void split8(const float* src, bf16x8& hi, bf16x8& lo) {
    float f[8];
    *(float4*)&f[0] = *(const float4*)src;
    *(float4*)&f[4] = *(const float4*)(src + 4);
    FW H, L;
#pragma unroll
    for (int i = 0; i < 4; ++i) {
        float a = f[2*i], b = f[2*i+1];
        H.w[i] = packbf2(a, b);
        L.w[i] = packbf2(a - trunc_bf(a), b - trunc_bf(b));
    }
    hi = H.v; lo = L.v;
}

#define MFMA(A, B, C) __builtin_amdgcn_mfma_f32_16x16x32_bf16((A), (B), (C), 0, 0, 0)

// Gate-interleaved MFMA LSTM: gate rows permuted to row' = 4*unit + gate, so a
// 16x16 C-tile holds 4 units x 4 gates and each lane (col=batch n, rows 4qg+r)
// ends the MFMA with ALL FOUR gate preacts of unit 4w+qg -> elementwise fuses
// in-lane (c-state in registers), h written back as bf16 hi/lo u16s directly
// into the fragment layout. No gate LDS array, 1 barrier/step, 16 balanced
// waves (18 MFMA each, 3 independent acc chains), 1 block/CU, 4 waves/SIMD.
__global__ void __launch_bounds__(1024)
lstm2_fused(
    const float* __restrict__ x,      // [B, SEQ, 1]
    const float* __restrict__ w_ih0,  // [256, 1]
    const float* __restrict__ w_hh0,  // [256, 64]
    const float* __restrict__ b_ih0,  // [256]
    const float* __restrict__ b_hh0,  // [256]
    const float* __restrict__ w_ih1,  // [256, 64]
    const float* __restrict__ w_hh1,  // [256, 64]
    const float* __restrict__ b_ih1,  // [256]
    const float* __restrict__ b_hh1,  // [256]
    const float* __restrict__ fc_w,   // [12, 64]
    const float* __restrict__ fc_b,   // [12]
    float* __restrict__ out)          // [B, 12]
{
    __shared__ float xs[BT][XST];          // 16.4 KB
    __shared__ u32   h0f[2][2][16][KPD];   // 9 KB  [dbuf][hi/lo][batch-row n][dword]
    __shared__ u32   h1f[2][2][16][KPD];   // 9 KB
    __shared__ float h1last[BT][HID + 4];  // 2.1 KB

    const int tid  = threadIdx.x;
    const int w    = tid >> 6;        // wave = unit band (units 4w..4w+3)
    const int lane = tid & 63;
    const int n    = lane & 15;       // MFMA A-row' / B-col (batch) lane index
    const int qg   = lane >> 4;       // k-group / C-row quad (0..3)
    const int b0   = blockIdx.x * BT;

    // ---- A fragments, permuted rows: row' = 16w + n -> unit 4w+(n>>2), gate n&3
    const int arow = (n & 3) * 64 + 4 * w + (n >> 2);   // original gate-row index
    bf16x8 A0h[2], A0l[2], AIh[2], AIl[2], AHh[2], AHl[2];
#pragma unroll
    for (int kt = 0; kt < 2; ++kt) {
        split8(&w_hh0[arow * HID + 32*kt + 8*qg], A0h[kt], A0l[kt]);
        split8(&w_ih1[arow * HID + 32*kt + 8*qg], AIh[kt], AIl[kt]);
        split8(&w_hh1[arow * HID + 32*kt + 8*qg], AHh[kt], AHl[kt]);
    }

    // ---- ew constants for this lane's unit (4w+qg), gates r = 0..3 ----
    const int uo = 4 * w + qg;        // owned unit
    float wih[4], bia0[4], bia1[4];
#pragma unroll
    for (int r = 0; r < 4; ++r) {
        const int row = 64 * r + uo;  // original row of gate r
        wih[r]  = w_ih0[row];
        bia0[r] = b_ih0[row] + b_hh0[row];
        bia1[r] = b_ih1[row] + b_hh1[row];
    }

    // ---- stage x; zero frag buffers (batch rows 8..15 stay zero forever) ----
    for (int i = tid; i < BT * SEQ; i += 1024) {
        int b = i >> 9, t = i & (SEQ - 1);
        xs[b][t] = x[(size_t)(b0 + b) * SEQ + t];
    }
    for (int i = tid; i < 2 * 2 * 16 * KPD; i += 1024) {
        ((u32*)h0f)[i] = 0u;
        ((u32*)h1f)[i] = 0u;
    }
    float c0 = 0.f, c1 = 0.f;
    __syncthreads();

    // ===== prologue: h0(0) from x(0) only (h0(-1)=0); h1(-1)=0 already =====
    if (n < BT) {
        float xv = xs[n][0];
        float ig = sigf(fmaf(xv, wih[0], bia0[0]));
        float gg = tanhf_fast(fmaf(xv, wih[2], bia0[2]));
        float og = sigf(fmaf(xv, wih[3], bia0[3]));
        c0 = ig * gg;                                  // f*c_prev = 0
        float h0n = og * tanhf_fast(c0);
        ((u16*)h0f[0][0][n])[uo] = bf_hi(h0n);
        ((u16*)h0f[0][1][n])[uo] = bf_lo(h0n);
    }
    __syncthreads();

    for (int t = 0; t < SEQ; ++t) {
        const int cur = t & 1, nxt = cur ^ 1;
        const int tx  = (t + 1 < SEQ) ? (t + 1) : (SEQ - 1);  // clamped dummy at t=511

        // acc0 = W_hh0.h0(t) ; acc1 = W_ih1.h0(t) ; acc2 = W_hh1.h1(t-1)
        f32x4 z = {0.f, 0.f, 0.f, 0.f};
        f32x4 acc0 = z, acc1 = z, acc2 = z;
#pragma unroll
        for (int kt = 0; kt < 2; ++kt) {
            FW B0h, B0l, B1h, B1l;
            B0h.q = *(const uint4*)&h0f[cur][0][n][16*kt + 4*qg];
            B0l.q = *(const uint4*)&h0f[cur][1][n][16*kt + 4*qg];
            B1h.q = *(const uint4*)&h1f[cur][0][n][16*kt + 4*qg];
            B1l.q = *(const uint4*)&h1f[cur][1][n][16*kt + 4*qg];
            acc0 = MFMA(A0h[kt], B0h.v, acc0);
            acc1 = MFMA(AIh[kt], B0h.v, acc1);
            acc2 = MFMA(AHh[kt], B1h.v, acc2);
            acc0 = MFMA(A0h[kt], B0l.v, acc0);
            acc1 = MFMA(AIh[kt], B0l.v, acc1);
            acc2 = MFMA(AHh[kt], B1l.v, acc2);
            acc0 = MFMA(A0l[kt], B0h.v, acc0);
            acc1 = MFMA(AIl[kt], B0h.v, acc1);
            acc2 = MFMA(AHl[kt], B1h.v, acc2);
        }

        // ===== in-lane elementwise: this lane owns (unit uo, batch n) =====
        if (n < BT) {
            const float xv = xs[n][tx];
            float ig = sigf(acc0[0] + fmaf(xv, wih[0], bia0[0]));
            float fg = sigf(acc0[1] + fmaf(xv, wih[1], bia0[1]));
            float gg = tanhf_fast(acc0[2] + fmaf(xv, wih[2], bia0[2]));
            float og = sigf(acc0[3] + fmaf(xv, wih[3], bia0[3]));
            c0 = fg * c0 + ig * gg;
            float h0n = og * tanhf_fast(c0);           // h0(t+1)

            float s0 = acc1[0] + acc2[0] + bia1[0];
            float s1 = acc1[1] + acc2[1] + bia1[1];
            float s2 = acc1[2] + acc2[2] + bia1[2];
            float s3 = acc1[3] + acc2[3] + bia1[3];
            float ig1 = sigf(s0);
            float fg1 = sigf(s1);
            float gg1 = tanhf_fast(s2);
            float og1 = sigf(s3);
            c1 = fg1 * c1 + ig1 * gg1;
            float h1n = og1 * tanhf_fast(c1);          // h1(t)

            ((u16*)h0f[nxt][0][n])[uo] = bf_hi(h0n);
            ((u16*)h0f[nxt][1][n])[uo] = bf_lo(h0n);
            ((u16*)h1f[nxt][0][n])[uo] = bf_hi(h1n);
            ((u16*)h1f[nxt][1][n])[uo] = bf_lo(h1n);
            if (t == SEQ - 1) h1last[n][uo] = h1n;
        }
        __syncthreads();    // single barrier per step (dbuf removes WAR hazard)
    }

    // ===== final projection: out[b][o] = fc_b[o] + h1(511) . fc_w[o] =====
    if (tid < BT * NOUT) {
        int b = tid / NOUT, o = tid % NOUT;
        float acc = fc_b[o];
#pragma unroll
        for (int j = 0; j < HID; ++j)
            acc = fmaf(fc_w[o * HID + j], h1last[b][j], acc);
        out[(size_t)(b0 + b) * NOUT + o] = acc;
    }
}

extern "C" void kernel_launch(void* const* d_in, const int* in_sizes, int n_in,
                              void* d_out, int out_size, void* d_ws, size_t ws_size,
                              hipStream_t stream) {
    const float* x     = (const float*)d_in[0];
    const float* w_ih0 = (const float*)d_in[1];
    const float* w_hh0 = (const float*)d_in[2];
    const float* b_ih0 = (const float*)d_in[3];
    const float* b_hh0 = (const float*)d_in[4];
    const float* w_ih1 = (const float*)d_in[5];
    const float* w_hh1 = (const float*)d_in[6];
    const float* b_ih1 = (const float*)d_in[7];
    const float* b_hh1 = (const float*)d_in[8];
    const float* fc_w  = (const float*)d_in[9];
    const float* fc_b  = (const float*)d_in[10];

    const int B = in_sizes[0] / SEQ;          // 2048
    dim3 grid(B / BT);                        // 256 blocks -> 1 block/CU, 16 waves
    lstm2_fused<<<grid, 1024, 0, stream>>>(x, w_ih0, w_hh0, b_ih0, b_hh0,
                                           w_ih1, w_hh1, b_ih1, b_hh1,
                                           fc_w, fc_b, (float*)d_out);
}

// Round 10
// 855.167 us; speedup vs baseline: 1.1770x; 1.1770x over previous
//
#include <hip/hip_runtime.h>

#define BT    8      // batch tile per block
#define HID   64
#define SEQ   512
#define NOUT  12
#define GRS   9      // gate-row stride in floats (8 batches + 1 pad)

typedef float  f32x4  __attribute__((ext_vector_type(4)));
typedef short  bf16x8 __attribute__((ext_vector_type(8)));
typedef unsigned int u32;

union FW { bf16x8 v; u32 w[4]; uint4 q; };

__device__ __forceinline__ float sigf(float x)       { return 1.f / (1.f + __expf(-x)); }
__device__ __forceinline__ float tanhf_fast(float x) { return 1.f - 2.f / (1.f + __expf(2.f * x)); }
__device__ __forceinline__ u32  packbf2(float a, float b) {
    return (__float_as_uint(a) >> 16) | (__float_as_uint(b) & 0xFFFF0000u);
}
__device__ __forceinline__ float trunc_bf(float a) {
    return __uint_as_float(__float_as_uint(a) & 0xFFFF0000u);
}
// Split 8 consecutive f32 into hi/lo bf16x8 fragments (element j <-> k-offset j).
__device__ __forceinline__ void split8(const float* src, bf16x8& hi, bf16x8& lo) {
    float f[8];
    *(float4*)&f[0] = *(const float4*)src;
    *(float4*)&f[4] = *(const float4*)(src + 4);
    FW H, L;
#pragma unroll
    for (int i = 0; i < 4; ++i) {
        float a = f[2*i], b = f[2*i+1];
        H.w[i] = packbf2(a, b);
        L.w[i] = packbf2(a - trunc_bf(a), b - trunc_bf(b));
    }
    hi = H.v; lo = L.v;
}

#define MFMA(A, B, C) __builtin_amdgcn_mfma_f32_16x16x32_bf16((A), (B), (C), 0, 0, 0)

// Fragment store: per (dbuf, layer, hi/lo, kt) a 256-dword block of 64 x 16B
// chunks. The chunk MFMA-lane L consumes sits at position swz(L) = L ^ (L>>3):
// reads are lane-linear (<=2-way banks); the XOR makes the ew-side u32 writes
// also <=2-way (banks 4*((eb^2qg)&7)+jh). Pure permutation of round-8 content.
#define HFB(db, ly, hl, kt) ((((((db)*2 + (ly))*2 + (hl))*2 + (kt)) << 8))
__device__ __forceinline__ int swz(int c) { return c ^ (c >> 3); }

// Round-8 structure: 16 balanced waves (1024 thr), 1 block/CU, 4 waves/SIMD.
// Wave w computes the 16-row band of BOTH layer GEMMs (18 MFMA, split-bf16).
// Gates round-trip through conflict-free gl; ew phase uses all 1024 threads
// (1 unit-layer each, c-state in registers). Only change vs round 8: the
// h-fragment LDS layout is the swizzled lane-linear one above.
__global__ void __launch_bounds__(1024)
lstm2_fused(
    const float* __restrict__ x,      // [B, SEQ, 1]
    const float* __restrict__ w_ih0,  // [256, 1]
    const float* __restrict__ w_hh0,  // [256, 64]
    const float* __restrict__ b_ih0,  // [256]
    const float* __restrict__ b_hh0,  // [256]
    const float* __restrict__ w_ih1,  // [256, 64]
    const float* __restrict__ w_hh1,  // [256, 64]
    const float* __restrict__ b_ih1,  // [256]
    const float* __restrict__ b_hh1,  // [256]
    const float* __restrict__ fc_w,   // [12, 64]
    const float* __restrict__ fc_b,   // [12]
    float* __restrict__ out)          // [B, 12]
{
    __shared__ float xs[BT][SEQ];          // 16 KB
    __shared__ u32   hf[4096];             // 16 KB [dbuf][layer][hi/lo][kt][chunk]
    __shared__ float gl[2][256][GRS];      // 18.4 KB [layer][gate-row][batch]
    __shared__ float h1last[BT][HID + 4];  // 2.1 KB

    const int tid  = threadIdx.x;
    const int wid  = tid >> 6;        // row-tile band (0..15)
    const int lane = tid & 63;
    const int n    = lane & 15;       // MFMA A-row / B-col (batch) lane index
    const int qg   = lane >> 4;       // lane k-group (0..3)
    const int b0   = blockIdx.x * BT;

    // ew role: thread <-> (layer, batch, unit)
    const int el = tid >> 9;          // 0..1
    const int eb = (tid >> 6) & 7;    // 0..7
    const int eu = lane;              // 0..63

    // ---- A fragments: 12 x bf16x8 = 48 regs (loop-invariant) ----
    const int arow = 16 * wid + n;
    bf16x8 A0h[2], A0l[2], AIh[2], AIl[2], AHh[2], AHl[2];
#pragma unroll
    for (int kt = 0; kt < 2; ++kt) {
        split8(&w_hh0[arow * HID + 32*kt + 8*qg], A0h[kt], A0l[kt]);
        split8(&w_ih1[arow * HID + 32*kt + 8*qg], AIh[kt], AIl[kt]);
        split8(&w_hh1[arow * HID + 32*kt + 8*qg], AHh[kt], AHl[kt]);
    }

    // ---- ew constants: unified formula, wihq=0 for layer 1 ----
    float biasq[4], wihq[4];
#pragma unroll
    for (int q = 0; q < 4; ++q) {
        int row = eu + 64 * q;
        if (el == 0) { biasq[q] = b_ih0[row] + b_hh0[row]; wihq[q] = w_ih0[row]; }
        else         { biasq[q] = b_ih1[row] + b_hh1[row]; wihq[q] = 0.f; }
    }

    // ---- frag addressing (loop-invariant) ----
    const int rb  = swz(lane) << 2;                 // read: my chunk, dword offset
    const int wkt = eu >> 5;                        // write: target kt
    const int wc4 = (swz(((eu >> 3) & 3) * 16 + eb) << 2) + ((eu & 7) >> 1);
    const bool wr = !(eu & 1);                      // even-unit lanes store pairs

    // ---- stage x; zero frag buffers ----
    for (int i = tid; i < BT * SEQ; i += 1024) {
        int b = i >> 9, t = i & (SEQ - 1);
        xs[b][t] = x[(size_t)(b0 + b) * SEQ + t];
    }
    for (int i = tid; i < 4096; i += 1024) hf[i] = 0u;
    float c = 0.f, h = 0.f;
    __syncthreads();

    // ===== prologue: h0(0) from x(0) only (h0(-1)=0); h1(-1)=0 already =====
    if (el == 0) {
        float xv = xs[eb][0];
        float ig = sigf(fmaf(xv, wihq[0], biasq[0]));
        float gg = tanhf_fast(fmaf(xv, wihq[2], biasq[2]));
        float og = sigf(fmaf(xv, wihq[3], biasq[3]));
        c = ig * gg;
        h = og * tanhf_fast(c);
    }
    {
        float hp = __int_as_float(__builtin_amdgcn_mov_dpp(__float_as_int(h), 0xB1, 0xF, 0xF, true));
        if (el == 0 && wr) {
            hf[HFB(0, 0, 0, wkt) + wc4] = packbf2(h, hp);
            hf[HFB(0, 0, 1, wkt) + wc4] = packbf2(h - trunc_bf(h), hp - trunc_bf(hp));
        }
    }
    __syncthreads();

    for (int t = 0; t < SEQ; ++t) {
        const int cur = t & 1, nxt = cur ^ 1;
        const int tx  = (t + 1 < SEQ) ? (t + 1) : (SEQ - 1);  // clamped dummy at t=511

        // ===== compute: acc0 = W_hh0.h0(t) ; acc1 = W_ih1.h0(t) + W_hh1.h1(t-1)
        f32x4 z = {0.f, 0.f, 0.f, 0.f};
        f32x4 acc0 = z, acc1 = z;
        {
            FW Bh[2], Bl[2];
#pragma unroll
            for (int kt = 0; kt < 2; ++kt) {
                Bh[kt].q = *(const uint4*)&hf[HFB(cur, 0, 0, kt) + rb];
                Bl[kt].q = *(const uint4*)&hf[HFB(cur, 0, 1, kt) + rb];
            }
#pragma unroll
            for (int kt = 0; kt < 2; ++kt) {
                acc0 = MFMA(A0h[kt], Bh[kt].v, acc0);
                acc0 = MFMA(A0h[kt], Bl[kt].v, acc0);
                acc0 = MFMA(A0l[kt], Bh[kt].v, acc0);
                acc1 = MFMA(AIh[kt], Bh[kt].v, acc1);
                acc1 = MFMA(AIh[kt], Bl[kt].v, acc1);
                acc1 = MFMA(AIl[kt], Bh[kt].v, acc1);
            }
#pragma unroll
            for (int kt = 0; kt < 2; ++kt) {
                Bh[kt].q = *(const uint4*)&hf[HFB(cur, 1, 0, kt) + rb];
                Bl[kt].q = *(const uint4*)&hf[HFB(cur, 1, 1, kt) + rb];
            }
#pragma unroll
            for (int kt = 0; kt < 2; ++kt) {
                acc1 = MFMA(AHh[kt], Bh[kt].v, acc1);
                acc1 = MFMA(AHh[kt], Bl[kt].v, acc1);
                acc1 = MFMA(AHl[kt], Bh[kt].v, acc1);
            }
        }
        // store gate pre-activations (C/D: col=n, tile-row=4qg+r); <=2-way banks
        if (n < BT) {
#pragma unroll
            for (int r = 0; r < 4; ++r) {
                gl[0][16*wid + 4*qg + r][n] = acc0[r];
                gl[1][16*wid + 4*qg + r][n] = acc1[r];
            }
        }
        __syncthreads();

        // ===== ew: this thread retires (el, eb, eu) =====
        {
            float xv = xs[eb][tx];
            float g0 = gl[el][eu      ][eb];
            float g1 = gl[el][eu +  64][eb];
            float g2 = gl[el][eu + 128][eb];
            float g3 = gl[el][eu + 192][eb];
            float ig = sigf(g0 + fmaf(xv, wihq[0], biasq[0]));
            float fg = sigf(g1 + fmaf(xv, wihq[1], biasq[1]));
            float gg = tanhf_fast(g2 + fmaf(xv, wihq[2], biasq[2]));
            float og = sigf(g3 + fmaf(xv, wihq[3], biasq[3]));
            c = fg * c + ig * gg;
            h = og * tanhf_fast(c);
            // pack (h, partner-h) into bf16 hi/lo words; even-unit lanes store
            float hp = __int_as_float(__builtin_amdgcn_mov_dpp(__float_as_int(h), 0xB1, 0xF, 0xF, true));
            if (wr) {
                hf[HFB(nxt, el, 0, wkt) + wc4] = packbf2(h, hp);
                hf[HFB(nxt, el, 1, wkt) + wc4] = packbf2(h - trunc_bf(h), hp - trunc_bf(hp));
            }
        }
        __syncthreads();
    }

    // layer-1 ew threads still hold h1(511) in register
    if (el == 1) h1last[eb][eu] = h;
    __syncthreads();

    // ===== final projection: out[b][o] = fc_b[o] + h1(511) . fc_w[o] =====
    if (tid < BT * NOUT) {
        int b = tid / NOUT, o = tid % NOUT;
        float acc = fc_b[o];
#pragma unroll
        for (int j = 0; j < HID; ++j)
            acc = fmaf(fc_w[o * HID + j], h1last[b][j], acc);
        out[(size_t)(b0 + b) * NOUT + o] = acc;
    }
}

extern "C" void kernel_launch(void* const* d_in, const int* in_sizes, int n_in,
                              void* d_out, int out_size, void* d_ws, size_t ws_size,
                              hipStream_t stream) {
    const float* x     = (const float*)d_in[0];
    const float* w_ih0 = (const float*)d_in[1];
    const float* w_hh0 = (const float*)d_in[2];
    const float* b_ih0 = (const float*)d_in[3];
    const float* b_hh0 = (const float*)d_in[4];
    const float* w_ih1 = (const float*)d_in[5];
    const float* w_hh1 = (const float*)d_in[6];
    const float* b_ih1 = (const float*)d_in[7];
    const float* b_hh1 = (const float*)d_in[8];
    const float* fc_w  = (const float*)d_in[9];
    const float* fc_b  = (const float*)d_in[10];

    const int B = in_sizes[0] / SEQ;          // 2048
    dim3 grid(B / BT);                        // 256 blocks -> 1 block/CU, 16 waves
    lstm2_fused<<<grid, 1024, 0, stream>>>(x, w_ih0, w_hh0, b_ih0, b_hh0,
                                           w_ih1, w_hh1, b_ih1, b_hh1,
                                           fc_w, fc_b, (float*)d_out);
}